// Round 8
// baseline (77.306 us; speedup 1.0000x reference)
//
#include <hip/hip_runtime.h>
#include <hip/hip_cooperative_groups.h>

namespace cg = cooperative_groups;

#define N_SEQS 2048
#define SEQ_LEN 512
#define NAA 20
#define NS 21                  // states incl. gap (pad bin)
#define MPOS 100
#define G 4                    // tile side
#define NG 25                  // MPOS / G
#define NTILE 325              // NG*(NG+1)/2 tile-pairs (ti<=tj)
#define HB (NS * NS)           // 441
#define POSB 64                // pos blocks (8 positions each)
#define NBLK (NTILE + POSB)    // 389
#define PACKB 256              // phase-1 packing blocks

// ===========================================================================
// Cooperative single-dispatch kernel.
//  phase 1: blocks 0..255 transpose msa[:, 0:100] -> cols[100][2048] (bytes)
//  grid.sync()
//  phase 2: blocks [0,NTILE): MI 4x4 tile-pairs, COALESCED packed reads,
//           2-way seq-split histograms (R7 structure).
//           blocks [NTILE,NBLK): 8 positions each: pssm/cons/MI-row zeroing.
// ===========================================================================
__global__ __launch_bounds__(512) void coop_kernel(const int* __restrict__ msa,
                                                   const float* __restrict__ pc,
                                                   unsigned char* __restrict__ cols,
                                                   float* __restrict__ pssm,
                                                   float* __restrict__ cons,
                                                   float* __restrict__ mi) {
    __shared__ int h_s[2 * 16 * HB];   // 56448 B

    const int tid = threadIdx.x;
    const int w = tid >> 6;
    const int lane = tid & 63;
    const int bid = blockIdx.x;

    // ---------------- phase 1: pack (blocks 0..255, 8 seqs each) -----------
    if (bid < PACKB) {
        unsigned char* T = (unsigned char*)h_s;   // [8][104] byte tile
        const int r = w;                          // one wave per row
        const int s0 = bid * 8;
        if (lane < 25) {
            const int4 v = *(const int4*)(msa + (size_t)(s0 + r) * SEQ_LEN + 4 * lane);
            T[r * 104 + 4 * lane + 0] = (unsigned char)v.x;
            T[r * 104 + 4 * lane + 1] = (unsigned char)v.y;
            T[r * 104 + 4 * lane + 2] = (unsigned char)v.z;
            T[r * 104 + 4 * lane + 3] = (unsigned char)v.w;
        }
        __syncthreads();
        if (tid < MPOS) {
            unsigned long long x = 0;
#pragma unroll
            for (int rr = 0; rr < 8; ++rr)
                x |= (unsigned long long)T[rr * 104 + tid] << (8 * rr);
            *(unsigned long long*)(cols + (size_t)tid * N_SEQS + s0) = x;
        }
    }

    cg::this_grid().sync();

    if (bid < NTILE) {
        // ======================== MI tile-pair part ========================
        int t = bid, ti = 0, off = 0;
        while (off + (NG - ti) <= t) { off += NG - ti; ++ti; }
        const int tj = ti + (t - off);
        const int i0 = ti * G, j0 = tj * G;
        const bool diag = (ti == tj);

        for (int k = tid; k < 2 * 16 * HB; k += 512) h_s[k] = 0;
        __syncthreads();

        const int half = tid >> 8;     // 0 or 1 (waves 0-3 vs 4-7)
        const int q = tid & 255;
        int* H = h_s + half * (16 * HB);
        const int s = half * 1024 + q * 4;   // 4 consecutive seqs per thread

        unsigned int A[4], B[4];
#pragma unroll
        for (int c = 0; c < 4; ++c)
            A[c] = *(const unsigned int*)(cols + (size_t)(i0 + c) * N_SEQS + s);
#pragma unroll
        for (int c = 0; c < 4; ++c)
            B[c] = *(const unsigned int*)(cols + (size_t)(j0 + c) * N_SEQS + s);

#pragma unroll
        for (int k = 0; k < 4; ++k) {
            const int sh = 8 * k;
            const int a0 = (int)((A[0] >> sh) & 255) * NS;
            const int a1 = (int)((A[1] >> sh) & 255) * NS;
            const int a2 = (int)((A[2] >> sh) & 255) * NS;
            const int a3 = (int)((A[3] >> sh) & 255) * NS;
            const int b0 = (int)((B[0] >> sh) & 255);
            const int b1 = (int)((B[1] >> sh) & 255);
            const int b2 = (int)((B[2] >> sh) & 255);
            const int b3 = (int)((B[3] >> sh) & 255);
#define UPD(PI, PJ, AA, BB) atomicAdd(&H[(PI * 4 + PJ) * HB + AA + BB], 1)
            UPD(0, 0, a0, b0); UPD(0, 1, a0, b1); UPD(0, 2, a0, b2); UPD(0, 3, a0, b3);
            UPD(1, 0, a1, b0); UPD(1, 1, a1, b1); UPD(1, 2, a1, b2); UPD(1, 3, a1, b3);
            UPD(2, 0, a2, b0); UPD(2, 1, a2, b1); UPD(2, 2, a2, b2); UPD(2, 3, a2, b3);
            UPD(3, 0, a3, b0); UPD(3, 1, a3, b1); UPD(3, 2, a3, b2); UPD(3, 3, a3, b3);
#undef UPD
        }
        __syncthreads();

        // finish: wave w handles pairs 2w and 2w+1
#pragma unroll
        for (int qq = 0; qq < 2; ++qq) {
            const int p = w * 2 + qq;
            const int pi = p >> 2, pj = p & 3;
            if (diag && pi >= pj) continue;       // wave-uniform skip
            const int* hA = h_s + p * HB;
            const int* hB = h_s + 16 * HB + p * HB;

            float mterm = 0.f, tpart = 0.f;
            if (lane < NAA) {
                int ssum = 0;
#pragma unroll
                for (int b = 0; b < NAA; ++b)
                    ssum += hA[lane * NS + b] + hB[lane * NS + b];
                if (ssum > 0) {
                    const float R = (float)ssum;
                    tpart = R;
                    mterm = R * __log2f(R);
                }
            } else if (lane >= 32 && lane < 32 + NAA) {
                const int c = lane - 32;
                int ssum = 0;
#pragma unroll
                for (int a = 0; a < NAA; ++a)
                    ssum += hA[a * NS + c] + hB[a * NS + c];
                if (ssum > 0) {
                    const float C = (float)ssum;
                    mterm = C * __log2f(C);
                }
            }

            float part = -mterm;   // Sum J lgJ - Sum Ra lgRa - Sum Cb lgCb
#pragma unroll
            for (int u = 0; u < 7; ++u) {
                const int k2 = lane + (u << 6);
                if (k2 < NAA * NAA) {
                    const int row = k2 / NAA;
                    const int col = k2 - row * NAA;
                    const int J = hA[row * NS + col] + hB[row * NS + col];
                    if (J > 0) {
                        const float fJ = (float)J;
                        part += fJ * __log2f(fJ);
                    }
                }
            }
#pragma unroll
            for (int o = 32; o; o >>= 1) {
                part += __shfl_down(part, o, 64);
                tpart += __shfl_down(tpart, o, 64);
            }
            if (lane == 0) {
                const float m = (tpart > 0.f)
                                    ? __fdividef(part, tpart) + __log2f(tpart)
                                    : 0.f;
                mi[(size_t)(i0 + pi) * SEQ_LEN + (j0 + pj)] = m;
                mi[(size_t)(j0 + pj) * SEQ_LEN + (i0 + pi)] = m;
            }
        }
    } else {
        // ========================== position part ==========================
        const int pb = bid - NTILE;      // 0..63
        const int i0 = pb * 8;

        for (int r = 0; r < 8; ++r) {
            const int i = i0 + r;
            float* rowp = mi + (size_t)i * SEQ_LEN;
            if (i < MPOS) {
                const int c = MPOS + tid;
                if (c < SEQ_LEN) rowp[c] = 0.f;
                if (tid == 0) rowp[i] = 0.f;
            } else {
                if (tid < SEQ_LEN / 4)
                    ((float4*)rowp)[tid] = make_float4(0.f, 0.f, 0.f, 0.f);
            }
        }

        for (int k = tid; k < 8 * 8 * NS; k += 512) h_s[k] = 0;
        __syncthreads();

        int* h = h_s + w * (8 * NS);
#pragma unroll
        for (int k = 0; k < 4; ++k) {
            const int s = tid + (k << 9);
            const int* rp = msa + (size_t)s * SEQ_LEN + i0;
            const int4 v0 = *(const int4*)rp;
            const int4 v1 = *(const int4*)(rp + 4);
            atomicAdd(&h[0 * NS + v0.x], 1);
            atomicAdd(&h[1 * NS + v0.y], 1);
            atomicAdd(&h[2 * NS + v0.z], 1);
            atomicAdd(&h[3 * NS + v0.w], 1);
            atomicAdd(&h[4 * NS + v1.x], 1);
            atomicAdd(&h[5 * NS + v1.y], 1);
            atomicAdd(&h[6 * NS + v1.z], 1);
            atomicAdd(&h[7 * NS + v1.w], 1);
        }
        __syncthreads();

        float* cntf = (float*)(h_s + 2048);
        if (tid < 8 * NAA) {
            const int p = tid / NAA, a = tid - p * NAA;
            const int idx = p * NS + a;
            int c = 0;
#pragma unroll
            for (int ww = 0; ww < 8; ++ww) c += h_s[ww * (8 * NS) + idx];
            cntf[tid] = (float)c;
            const float pcnt = 0.01f * pc[0];
            const float freq = __fdividef((float)c + pcnt, 2048.0f + pcnt * 20.0f);
            pssm[(size_t)(i0 + p) * NAA + a] = __logf(freq * 20.0f + 1e-10f);
        }
        __syncthreads();

        if (tid < 256) {
            const int p = tid >> 5, l = tid & 31;
            const float fc = (l < NAA) ? cntf[p * NAA + l] : 0.f;
            float tt = fc;
#pragma unroll
            for (int o = 16; o; o >>= 1) tt += __shfl_xor(tt, o, 32);
            const float ts2 = fmaxf(tt, 1.f);
            const float f = __fdividef(fc, ts2);
            float term = (l < NAA) ? -f * __log2f(f + 1e-10f) : 0.f;
#pragma unroll
            for (int o = 16; o; o >>= 1) term += __shfl_xor(term, o, 32);
            if (l == 0)
                cons[i0 + p] = (tt > 0.f) ? (1.f - term * 0.2313782131597592f) : 0.f;
        }
    }
}

// ===========================================================================
// Fallback (R7 kernel, non-cooperative, direct msa reads) — used only if the
// workspace is too small for the packed-column buffer.
// ===========================================================================
__global__ __launch_bounds__(512) void fused_kernel(const int* __restrict__ msa,
                                                    const float* __restrict__ pc,
                                                    float* __restrict__ pssm,
                                                    float* __restrict__ cons,
                                                    float* __restrict__ mi) {
    __shared__ int h_s[2 * 16 * HB];

    const int tid = threadIdx.x;
    const int w = tid >> 6;
    const int lane = tid & 63;
    const int bid = blockIdx.x;

    if (bid < NTILE) {
        int t = bid, ti = 0, off = 0;
        while (off + (NG - ti) <= t) { off += NG - ti; ++ti; }
        const int tj = ti + (t - off);
        const int i0 = ti * G, j0 = tj * G;
        const bool diag = (ti == tj);

        for (int k = tid; k < 2 * 16 * HB; k += 512) h_s[k] = 0;
        __syncthreads();

        const int half = tid >> 8;
        const int htid = tid & 255;
        int* H = h_s + half * (16 * HB);
#pragma unroll
        for (int k = 0; k < 4; ++k) {
            const int s = half * 1024 + htid + (k << 8);
            const int* rp = msa + (size_t)s * SEQ_LEN;
            const int4 va = *(const int4*)(rp + i0);
            const int4 vb = *(const int4*)(rp + j0);
            const int A0 = va.x * NS, A1 = va.y * NS, A2 = va.z * NS, A3 = va.w * NS;
#define UPD(PI, PJ, AA, BB) atomicAdd(&H[(PI * 4 + PJ) * HB + AA + BB], 1)
            UPD(0, 0, A0, vb.x); UPD(0, 1, A0, vb.y); UPD(0, 2, A0, vb.z); UPD(0, 3, A0, vb.w);
            UPD(1, 0, A1, vb.x); UPD(1, 1, A1, vb.y); UPD(1, 2, A1, vb.z); UPD(1, 3, A1, vb.w);
            UPD(2, 0, A2, vb.x); UPD(2, 1, A2, vb.y); UPD(2, 2, A2, vb.z); UPD(2, 3, A2, vb.w);
            UPD(3, 0, A3, vb.x); UPD(3, 1, A3, vb.y); UPD(3, 2, A3, vb.z); UPD(3, 3, A3, vb.w);
#undef UPD
        }
        __syncthreads();

#pragma unroll
        for (int q = 0; q < 2; ++q) {
            const int p = w * 2 + q;
            const int pi = p >> 2, pj = p & 3;
            if (diag && pi >= pj) continue;
            const int* hA = h_s + p * HB;
            const int* hB = h_s + 16 * HB + p * HB;

            float mterm = 0.f, tpart = 0.f;
            if (lane < NAA) {
                int ssum = 0;
#pragma unroll
                for (int b = 0; b < NAA; ++b)
                    ssum += hA[lane * NS + b] + hB[lane * NS + b];
                if (ssum > 0) {
                    const float R = (float)ssum;
                    tpart = R;
                    mterm = R * __log2f(R);
                }
            } else if (lane >= 32 && lane < 32 + NAA) {
                const int c = lane - 32;
                int ssum = 0;
#pragma unroll
                for (int a = 0; a < NAA; ++a)
                    ssum += hA[a * NS + c] + hB[a * NS + c];
                if (ssum > 0) {
                    const float C = (float)ssum;
                    mterm = C * __log2f(C);
                }
            }

            float part = -mterm;
#pragma unroll
            for (int u = 0; u < 7; ++u) {
                const int k2 = lane + (u << 6);
                if (k2 < NAA * NAA) {
                    const int row = k2 / NAA;
                    const int col = k2 - row * NAA;
                    const int J = hA[row * NS + col] + hB[row * NS + col];
                    if (J > 0) {
                        const float fJ = (float)J;
                        part += fJ * __log2f(fJ);
                    }
                }
            }
#pragma unroll
            for (int o = 32; o; o >>= 1) {
                part += __shfl_down(part, o, 64);
                tpart += __shfl_down(tpart, o, 64);
            }
            if (lane == 0) {
                const float m = (tpart > 0.f)
                                    ? __fdividef(part, tpart) + __log2f(tpart)
                                    : 0.f;
                mi[(size_t)(i0 + pi) * SEQ_LEN + (j0 + pj)] = m;
                mi[(size_t)(j0 + pj) * SEQ_LEN + (i0 + pi)] = m;
            }
        }
    } else {
        const int pb = bid - NTILE;
        const int i0 = pb * 8;

        for (int r = 0; r < 8; ++r) {
            const int i = i0 + r;
            float* rowp = mi + (size_t)i * SEQ_LEN;
            if (i < MPOS) {
                const int c = MPOS + tid;
                if (c < SEQ_LEN) rowp[c] = 0.f;
                if (tid == 0) rowp[i] = 0.f;
            } else {
                if (tid < SEQ_LEN / 4)
                    ((float4*)rowp)[tid] = make_float4(0.f, 0.f, 0.f, 0.f);
            }
        }

        for (int k = tid; k < 8 * 8 * NS; k += 512) h_s[k] = 0;
        __syncthreads();

        int* h = h_s + w * (8 * NS);
#pragma unroll
        for (int k = 0; k < 4; ++k) {
            const int s = tid + (k << 9);
            const int* rp = msa + (size_t)s * SEQ_LEN + i0;
            const int4 v0 = *(const int4*)rp;
            const int4 v1 = *(const int4*)(rp + 4);
            atomicAdd(&h[0 * NS + v0.x], 1);
            atomicAdd(&h[1 * NS + v0.y], 1);
            atomicAdd(&h[2 * NS + v0.z], 1);
            atomicAdd(&h[3 * NS + v0.w], 1);
            atomicAdd(&h[4 * NS + v1.x], 1);
            atomicAdd(&h[5 * NS + v1.y], 1);
            atomicAdd(&h[6 * NS + v1.z], 1);
            atomicAdd(&h[7 * NS + v1.w], 1);
        }
        __syncthreads();

        float* cntf = (float*)(h_s + 2048);
        if (tid < 8 * NAA) {
            const int p = tid / NAA, a = tid - p * NAA;
            const int idx = p * NS + a;
            int c = 0;
#pragma unroll
            for (int ww = 0; ww < 8; ++ww) c += h_s[ww * (8 * NS) + idx];
            cntf[tid] = (float)c;
            const float pcnt = 0.01f * pc[0];
            const float freq = __fdividef((float)c + pcnt, 2048.0f + pcnt * 20.0f);
            pssm[(size_t)(i0 + p) * NAA + a] = __logf(freq * 20.0f + 1e-10f);
        }
        __syncthreads();

        if (tid < 256) {
            const int p = tid >> 5, l = tid & 31;
            const float fc = (l < NAA) ? cntf[p * NAA + l] : 0.f;
            float tt = fc;
#pragma unroll
            for (int o = 16; o; o >>= 1) tt += __shfl_xor(tt, o, 32);
            const float ts2 = fmaxf(tt, 1.f);
            const float f = __fdividef(fc, ts2);
            float term = (l < NAA) ? -f * __log2f(f + 1e-10f) : 0.f;
#pragma unroll
            for (int o = 16; o; o >>= 1) term += __shfl_xor(term, o, 32);
            if (l == 0)
                cons[i0 + p] = (tt > 0.f) ? (1.f - term * 0.2313782131597592f) : 0.f;
        }
    }
}

// ---------------------------------------------------------------------------
extern "C" void kernel_launch(void* const* d_in, const int* in_sizes, int n_in,
                              void* d_out, int out_size, void* d_ws, size_t ws_size,
                              hipStream_t stream) {
    const int* msa = (const int*)d_in[0];
    const float* pc = (const float*)d_in[1];

    float* pssm = (float*)d_out;         // 512*20
    float* cons = pssm + SEQ_LEN * NAA;  // 512
    float* mi = cons + SEQ_LEN;          // 512*512

    unsigned char* cols = (unsigned char*)d_ws;   // 100*2048 = 200 KB

    if (ws_size >= (size_t)MPOS * N_SEQS) {
        void* args[] = {(void*)&msa, (void*)&pc, (void*)&cols,
                        (void*)&pssm, (void*)&cons, (void*)&mi};
        hipLaunchCooperativeKernel((void*)coop_kernel, dim3(NBLK), dim3(512),
                                   args, 0, stream);
    } else {
        fused_kernel<<<NBLK, 512, 0, stream>>>(msa, pc, pssm, cons, mi);
    }
}

// Round 9
// 22.231 us; speedup vs baseline: 3.4774x; 3.4774x over previous
//
#include <hip/hip_runtime.h>

#define N_SEQS 2048
#define SEQ_LEN 512
#define NAA 20
#define NS 21                  // states incl. gap (pad bin)
#define MPOS 100
#define G 4                    // tile side
#define NG 25                  // MPOS / G
#define NTILE 325              // NG*(NG+1)/2 tile-pairs (ti<=tj)
#define HB (NS * NS)           // 441
#define POSB 32                // pos blocks
#define PPB 16                 // positions per pos block (64B = 1 line/row)
#define NBLK (NTILE + POSB)    // 357

// ---------------------------------------------------------------------------
// Single fused kernel, 512 threads/block.
//  blocks [0, NTILE): MI 4x4 tile-pairs; 2-way seq-split histogram copies
//    (waves 0-3 seqs 0-1023 -> copy A, waves 4-7 -> copy B). Diagonal tiles
//    update only the 6 upper pairs.
//  blocks [NTILE, NBLK): 16 positions each -> pssm, conservation, MI zeroing.
// ---------------------------------------------------------------------------
__global__ __launch_bounds__(512) void fused_kernel(const int* __restrict__ msa,
                                                    const float* __restrict__ pc,
                                                    float* __restrict__ pssm,
                                                    float* __restrict__ cons,
                                                    float* __restrict__ mi) {
    __shared__ int h_s[2 * 16 * HB];   // 14112 ints = 56448 B

    const int tid = threadIdx.x;
    const int w = tid >> 6;
    const int lane = tid & 63;
    const int bid = blockIdx.x;

    if (bid < NTILE) {
        // ======================== MI tile-pair part ========================
        int t = bid, ti = 0, off = 0;
        while (off + (NG - ti) <= t) { off += NG - ti; ++ti; }
        const int tj = ti + (t - off);
        const int i0 = ti * G, j0 = tj * G;
        const bool diag = (ti == tj);

        for (int k = tid; k < 2 * 16 * HB; k += 512) h_s[k] = 0;
        __syncthreads();

        const int half = tid >> 8;      // 0 or 1 (waves 0-3 vs 4-7)
        const int htid = tid & 255;
        int* H = h_s + half * (16 * HB);

        // hoist all 8 band loads (MLP-8) before the DS-atomic burst
        int4 va[4], vb[4];
#pragma unroll
        for (int k = 0; k < 4; ++k) {
            const int s = half * 1024 + htid + (k << 8);
            const int* rp = msa + (size_t)s * SEQ_LEN;
            va[k] = *(const int4*)(rp + i0);
            vb[k] = *(const int4*)(rp + j0);
        }

#define UPD(P, AA, BB) atomicAdd(&H[(P) * HB + (AA) + (BB)], 1)
        if (diag) {
            // only upper pairs (pi<pj): p = pi*4+pj in {1,2,3,6,7,11}
#pragma unroll
            for (int k = 0; k < 4; ++k) {
                const int A0 = va[k].x * NS, A1 = va[k].y * NS, A2 = va[k].z * NS;
                const int b1 = vb[k].y, b2 = vb[k].z, b3 = vb[k].w;
                UPD(1, A0, b1); UPD(2, A0, b2); UPD(3, A0, b3);
                UPD(6, A1, b2); UPD(7, A1, b3);
                UPD(11, A2, b3);
            }
        } else {
#pragma unroll
            for (int k = 0; k < 4; ++k) {
                const int A0 = va[k].x * NS, A1 = va[k].y * NS,
                          A2 = va[k].z * NS, A3 = va[k].w * NS;
                const int b0 = vb[k].x, b1 = vb[k].y, b2 = vb[k].z, b3 = vb[k].w;
                UPD(0, A0, b0);  UPD(1, A0, b1);  UPD(2, A0, b2);  UPD(3, A0, b3);
                UPD(4, A1, b0);  UPD(5, A1, b1);  UPD(6, A1, b2);  UPD(7, A1, b3);
                UPD(8, A2, b0);  UPD(9, A2, b1);  UPD(10, A2, b2); UPD(11, A2, b3);
                UPD(12, A3, b0); UPD(13, A3, b1); UPD(14, A3, b2); UPD(15, A3, b3);
            }
        }
#undef UPD
        __syncthreads();

        // finish: wave w handles pairs 2w and 2w+1
#pragma unroll
        for (int q = 0; q < 2; ++q) {
            const int p = w * 2 + q;
            const int pi = p >> 2, pj = p & 3;
            if (diag && pi >= pj) continue;       // wave-uniform skip
            const int* hA = h_s + p * HB;
            const int* hB = h_s + 16 * HB + p * HB;

            float mterm = 0.f, tpart = 0.f;
            if (lane < NAA) {
                int ssum = 0;
#pragma unroll
                for (int b = 0; b < NAA; ++b)
                    ssum += hA[lane * NS + b] + hB[lane * NS + b];
                if (ssum > 0) {
                    const float R = (float)ssum;
                    tpart = R;
                    mterm = R * __log2f(R);
                }
            } else if (lane >= 32 && lane < 32 + NAA) {
                const int c = lane - 32;
                int ssum = 0;
#pragma unroll
                for (int a = 0; a < NAA; ++a)
                    ssum += hA[a * NS + c] + hB[a * NS + c];
                if (ssum > 0) {
                    const float C = (float)ssum;
                    mterm = C * __log2f(C);
                }
            }

            float part = -mterm;   // Sum J lgJ - Sum Ra lgRa - Sum Cb lgCb
#pragma unroll
            for (int u = 0; u < 7; ++u) {
                const int k2 = lane + (u << 6);
                if (k2 < NAA * NAA) {
                    const int row = k2 / NAA;
                    const int col = k2 - row * NAA;
                    const int J = hA[row * NS + col] + hB[row * NS + col];
                    if (J > 0) {
                        const float fJ = (float)J;
                        part += fJ * __log2f(fJ);
                    }
                }
            }
#pragma unroll
            for (int o = 32; o; o >>= 1) {
                part += __shfl_down(part, o, 64);
                tpart += __shfl_down(tpart, o, 64);
            }
            if (lane == 0) {
                const float m = (tpart > 0.f)
                                    ? __fdividef(part, tpart) + __log2f(tpart)
                                    : 0.f;
                mi[(size_t)(i0 + pi) * SEQ_LEN + (j0 + pj)] = m;
                mi[(size_t)(j0 + pj) * SEQ_LEN + (i0 + pi)] = m;
            }
        }
    } else {
        // ========================== position part ==========================
        const int pb = bid - NTILE;      // 0..31
        const int i0 = pb * PPB;         // 64B-aligned band of 16 positions

        // zero MI rows i0..i0+15 (race-free: MI blocks own off-diag [0,100)^2)
        for (int r = 0; r < PPB; ++r) {
            const int i = i0 + r;
            float* rowp = mi + (size_t)i * SEQ_LEN;
            if (i < MPOS) {
                if (tid < SEQ_LEN - MPOS) rowp[MPOS + tid] = 0.f;
                if (tid == 0) rowp[i] = 0.f;
            } else {
                if (tid < SEQ_LEN / 4)
                    ((float4*)rowp)[tid] = make_float4(0.f, 0.f, 0.f, 0.f);
            }
        }

        // per-wave 16x21 histograms: h_s[w*336 + p*21 + a]
        for (int k = tid; k < 8 * PPB * NS; k += 512) h_s[k] = 0;
        __syncthreads();

        int* h = h_s + w * (PPB * NS);
#pragma unroll
        for (int k = 0; k < 4; ++k) {
            const int s = tid + (k << 9);
            const int* rp = msa + (size_t)s * SEQ_LEN + i0;   // 64B read: 1 line
            const int4 v0 = ((const int4*)rp)[0];
            const int4 v1 = ((const int4*)rp)[1];
            const int4 v2 = ((const int4*)rp)[2];
            const int4 v3 = ((const int4*)rp)[3];
            atomicAdd(&h[0 * NS + v0.x], 1);
            atomicAdd(&h[1 * NS + v0.y], 1);
            atomicAdd(&h[2 * NS + v0.z], 1);
            atomicAdd(&h[3 * NS + v0.w], 1);
            atomicAdd(&h[4 * NS + v1.x], 1);
            atomicAdd(&h[5 * NS + v1.y], 1);
            atomicAdd(&h[6 * NS + v1.z], 1);
            atomicAdd(&h[7 * NS + v1.w], 1);
            atomicAdd(&h[8 * NS + v2.x], 1);
            atomicAdd(&h[9 * NS + v2.y], 1);
            atomicAdd(&h[10 * NS + v2.z], 1);
            atomicAdd(&h[11 * NS + v2.w], 1);
            atomicAdd(&h[12 * NS + v3.x], 1);
            atomicAdd(&h[13 * NS + v3.y], 1);
            atomicAdd(&h[14 * NS + v3.z], 1);
            atomicAdd(&h[15 * NS + v3.w], 1);
        }
        __syncthreads();

        float* cntf = (float*)(h_s + 4096);   // beyond the 2688 used ints
        if (tid < PPB * NAA) {                // 320 entries
            const int p = tid / NAA, a = tid - p * NAA;
            const int idx = p * NS + a;
            int c = 0;
#pragma unroll
            for (int ww = 0; ww < 8; ++ww) c += h_s[ww * (PPB * NS) + idx];
            cntf[tid] = (float)c;
            const float pcnt = 0.01f * pc[0];
            const float freq = __fdividef((float)c + pcnt, 2048.0f + pcnt * 20.0f);
            pssm[(size_t)(i0 + p) * NAA + a] = __logf(freq * 20.0f + 1e-10f);
        }
        __syncthreads();

        // conservation: 16 groups of 32 threads
        const int p = tid >> 5, l = tid & 31;
        const float fc = (l < NAA) ? cntf[p * NAA + l] : 0.f;
        float tt = fc;
#pragma unroll
        for (int o = 16; o; o >>= 1) tt += __shfl_xor(tt, o, 32);
        const float ts2 = fmaxf(tt, 1.f);
        const float f = __fdividef(fc, ts2);
        float term = (l < NAA) ? -f * __log2f(f + 1e-10f) : 0.f;
#pragma unroll
        for (int o = 16; o; o >>= 1) term += __shfl_xor(term, o, 32);
        if (l == 0)
            cons[i0 + p] = (tt > 0.f) ? (1.f - term * 0.2313782131597592f) : 0.f;
    }
}

// ---------------------------------------------------------------------------
extern "C" void kernel_launch(void* const* d_in, const int* in_sizes, int n_in,
                              void* d_out, int out_size, void* d_ws, size_t ws_size,
                              hipStream_t stream) {
    const int* msa = (const int*)d_in[0];
    const float* pc = (const float*)d_in[1];

    float* pssm = (float*)d_out;         // 512*20
    float* cons = pssm + SEQ_LEN * NAA;  // 512
    float* mi = cons + SEQ_LEN;          // 512*512

    fused_kernel<<<NBLK, 512, 0, stream>>>(msa, pc, pssm, cons, mi);
}

// Round 10
// 18.492 us; speedup vs baseline: 4.1805x; 1.2022x over previous
//
#include <hip/hip_runtime.h>

#define N_SEQS 2048
#define SEQ_LEN 512
#define NAA 20
#define NS 21                  // states incl. gap (pad bin)
#define MPOS 100
#define G 4                    // tile side
#define NG 25                  // MPOS / G
#define NTILE 325              // NG*(NG+1)/2 tile-pairs (ti<=tj)
#define HB (NS * NS)           // 441
#define POSB 64                // pos blocks (8 positions each)
#define NBLK (NTILE + POSB)    // 389

// ---------------------------------------------------------------------------
// Single fused kernel, 512 threads/block (R7 structure).
//  blocks [0, NTILE): MI 4x4 tile-pairs. 2-way seq split: waves 0-3 build
//    histogram copy A (seqs 0-1023), waves 4-7 copy B (seqs 1024-2047).
//    Diagonal tiles update only their 6 upper pairs.
//  blocks [NTILE, NBLK): 8 positions each -> pssm, conservation, MI zeroing.
// ---------------------------------------------------------------------------
__global__ __launch_bounds__(512) void fused_kernel(const int* __restrict__ msa,
                                                    const float* __restrict__ pc,
                                                    float* __restrict__ pssm,
                                                    float* __restrict__ cons,
                                                    float* __restrict__ mi) {
    __shared__ int h_s[2 * 16 * HB];   // 14112 ints = 56448 B

    const int tid = threadIdx.x;
    const int w = tid >> 6;
    const int lane = tid & 63;
    const int bid = blockIdx.x;

    if (bid < NTILE) {
        // ======================== MI tile-pair part ========================
        int t = bid, ti = 0, off = 0;
        while (off + (NG - ti) <= t) { off += NG - ti; ++ti; }
        const int tj = ti + (t - off);
        const int i0 = ti * G, j0 = tj * G;
        const bool diag = (ti == tj);

        for (int k = tid; k < 2 * 16 * HB; k += 512) h_s[k] = 0;
        __syncthreads();

        const int half = tid >> 8;      // 0 or 1 (waves 0-3 vs 4-7)
        const int htid = tid & 255;
        int* H = h_s + half * (16 * HB);

#define UPD(P, AA, BB) atomicAdd(&H[(P) * HB + (AA) + (BB)], 1)
        if (diag) {
            // only upper pairs (pi<pj): p = pi*4+pj in {1,2,3,6,7,11}
#pragma unroll
            for (int k = 0; k < 4; ++k) {
                const int s = half * 1024 + htid + (k << 8);
                const int* rp = msa + (size_t)s * SEQ_LEN;
                const int4 va = *(const int4*)(rp + i0);
                const int4 vb = *(const int4*)(rp + j0);
                const int A0 = va.x * NS, A1 = va.y * NS, A2 = va.z * NS;
                UPD(1, A0, vb.y); UPD(2, A0, vb.z); UPD(3, A0, vb.w);
                UPD(6, A1, vb.z); UPD(7, A1, vb.w);
                UPD(11, A2, vb.w);
            }
        } else {
#pragma unroll
            for (int k = 0; k < 4; ++k) {
                const int s = half * 1024 + htid + (k << 8);
                const int* rp = msa + (size_t)s * SEQ_LEN;
                const int4 va = *(const int4*)(rp + i0);
                const int4 vb = *(const int4*)(rp + j0);
                const int A0 = va.x * NS, A1 = va.y * NS,
                          A2 = va.z * NS, A3 = va.w * NS;
                UPD(0, A0, vb.x);  UPD(1, A0, vb.y);  UPD(2, A0, vb.z);  UPD(3, A0, vb.w);
                UPD(4, A1, vb.x);  UPD(5, A1, vb.y);  UPD(6, A1, vb.z);  UPD(7, A1, vb.w);
                UPD(8, A2, vb.x);  UPD(9, A2, vb.y);  UPD(10, A2, vb.z); UPD(11, A2, vb.w);
                UPD(12, A3, vb.x); UPD(13, A3, vb.y); UPD(14, A3, vb.z); UPD(15, A3, vb.w);
            }
        }
#undef UPD
        __syncthreads();

        // finish: wave w handles pairs 2w and 2w+1 (16 pairs over 8 waves)
#pragma unroll
        for (int q = 0; q < 2; ++q) {
            const int p = w * 2 + q;
            const int pi = p >> 2, pj = p & 3;
            if (diag && pi >= pj) continue;       // wave-uniform skip
            const int* hA = h_s + p * HB;
            const int* hB = h_s + 16 * HB + p * HB;

            float mterm = 0.f, tpart = 0.f;
            if (lane < NAA) {
                int ssum = 0;
#pragma unroll
                for (int b = 0; b < NAA; ++b)
                    ssum += hA[lane * NS + b] + hB[lane * NS + b];
                if (ssum > 0) {
                    const float R = (float)ssum;
                    tpart = R;
                    mterm = R * __log2f(R);
                }
            } else if (lane >= 32 && lane < 32 + NAA) {
                const int c = lane - 32;
                int ssum = 0;
#pragma unroll
                for (int a = 0; a < NAA; ++a)
                    ssum += hA[a * NS + c] + hB[a * NS + c];
                if (ssum > 0) {
                    const float C = (float)ssum;
                    mterm = C * __log2f(C);
                }
            }

            float part = -mterm;   // Sum J lgJ - Sum Ra lgRa - Sum Cb lgCb
#pragma unroll
            for (int u = 0; u < 7; ++u) {
                const int k2 = lane + (u << 6);
                if (k2 < NAA * NAA) {
                    const int row = k2 / NAA;
                    const int col = k2 - row * NAA;
                    const int J = hA[row * NS + col] + hB[row * NS + col];
                    if (J > 0) {
                        const float fJ = (float)J;
                        part += fJ * __log2f(fJ);
                    }
                }
            }
#pragma unroll
            for (int o = 32; o; o >>= 1) {
                part += __shfl_down(part, o, 64);
                tpart += __shfl_down(tpart, o, 64);
            }
            if (lane == 0) {
                const float m = (tpart > 0.f)
                                    ? __fdividef(part, tpart) + __log2f(tpart)
                                    : 0.f;
                mi[(size_t)(i0 + pi) * SEQ_LEN + (j0 + pj)] = m;
                mi[(size_t)(j0 + pj) * SEQ_LEN + (i0 + pi)] = m;
            }
        }
    } else {
        // ========================== position part ==========================
        const int pb = bid - NTILE;      // 0..63
        const int i0 = pb * 8;

        // zero MI rows i0..i0+7 (race-free: MI blocks own off-diag [0,100)^2)
        for (int r = 0; r < 8; ++r) {
            const int i = i0 + r;
            float* rowp = mi + (size_t)i * SEQ_LEN;
            if (i < MPOS) {
                const int c = MPOS + tid;
                if (c < SEQ_LEN) rowp[c] = 0.f;
                if (tid == 0) rowp[i] = 0.f;
            } else {
                if (tid < SEQ_LEN / 4)
                    ((float4*)rowp)[tid] = make_float4(0.f, 0.f, 0.f, 0.f);
            }
        }

        // per-wave 8x21 histograms: h_s[w*168 + p*21 + a]
        for (int k = tid; k < 8 * 8 * NS; k += 512) h_s[k] = 0;
        __syncthreads();

        int* h = h_s + w * (8 * NS);
#pragma unroll
        for (int k = 0; k < 4; ++k) {
            const int s = tid + (k << 9);
            const int* rp = msa + (size_t)s * SEQ_LEN + i0;
            const int4 v0 = *(const int4*)rp;
            const int4 v1 = *(const int4*)(rp + 4);
            atomicAdd(&h[0 * NS + v0.x], 1);
            atomicAdd(&h[1 * NS + v0.y], 1);
            atomicAdd(&h[2 * NS + v0.z], 1);
            atomicAdd(&h[3 * NS + v0.w], 1);
            atomicAdd(&h[4 * NS + v1.x], 1);
            atomicAdd(&h[5 * NS + v1.y], 1);
            atomicAdd(&h[6 * NS + v1.z], 1);
            atomicAdd(&h[7 * NS + v1.w], 1);
        }
        __syncthreads();

        float* cntf = (float*)(h_s + 2048);   // beyond the 1344 used ints
        if (tid < 8 * NAA) {
            const int p = tid / NAA, a = tid - p * NAA;
            const int idx = p * NS + a;
            int c = 0;
#pragma unroll
            for (int ww = 0; ww < 8; ++ww) c += h_s[ww * (8 * NS) + idx];
            cntf[tid] = (float)c;
            const float pcnt = 0.01f * pc[0];
            const float freq = __fdividef((float)c + pcnt, 2048.0f + pcnt * 20.0f);
            pssm[(size_t)(i0 + p) * NAA + a] = __logf(freq * 20.0f + 1e-10f);
        }
        __syncthreads();

        // conservation: 8 groups of 32 threads (waves 0-3)
        if (tid < 256) {
            const int p = tid >> 5, l = tid & 31;
            const float fc = (l < NAA) ? cntf[p * NAA + l] : 0.f;
            float tt = fc;
#pragma unroll
            for (int o = 16; o; o >>= 1) tt += __shfl_xor(tt, o, 32);
            const float ts2 = fmaxf(tt, 1.f);
            const float f = __fdividef(fc, ts2);
            float term = (l < NAA) ? -f * __log2f(f + 1e-10f) : 0.f;
#pragma unroll
            for (int o = 16; o; o >>= 1) term += __shfl_xor(term, o, 32);
            if (l == 0)
                cons[i0 + p] = (tt > 0.f) ? (1.f - term * 0.2313782131597592f) : 0.f;
        }
    }
}

// ---------------------------------------------------------------------------
extern "C" void kernel_launch(void* const* d_in, const int* in_sizes, int n_in,
                              void* d_out, int out_size, void* d_ws, size_t ws_size,
                              hipStream_t stream) {
    const int* msa = (const int*)d_in[0];
    const float* pc = (const float*)d_in[1];

    float* pssm = (float*)d_out;         // 512*20
    float* cons = pssm + SEQ_LEN * NAA;  // 512
    float* mi = cons + SEQ_LEN;          // 512*512

    fused_kernel<<<NBLK, 512, 0, stream>>>(msa, pc, pssm, cons, mi);
}

// Round 11
// 18.012 us; speedup vs baseline: 4.2920x; 1.0267x over previous
//
#include <hip/hip_runtime.h>

#define N_SEQS 2048
#define SEQ_LEN 512
#define NAA 20
#define NS 21                  // states incl. gap (pad bin)
#define MPOS 100
#define G 4                    // tile side
#define NG 25                  // MPOS / G
#define NTILE 325              // NG*(NG+1)/2 tile-pairs (ti<=tj)
#define HB (NS * NS)           // 441
#define POSB 64                // pos blocks (8 positions each)
#define NBLK (NTILE + POSB)    // 389

// ---------------------------------------------------------------------------
// Single fused kernel, 512 threads/block (R7 structure — best measured).
//  blocks [0, NTILE): MI 4x4 tile-pairs. 2-way seq split: waves 0-3 build
//    histogram copy A (seqs 0-1023), waves 4-7 copy B (seqs 1024-2047).
//  blocks [NTILE, NBLK): 8 positions each -> pssm, conservation, MI zeroing.
// ---------------------------------------------------------------------------
__global__ __launch_bounds__(512) void fused_kernel(const int* __restrict__ msa,
                                                    const float* __restrict__ pc,
                                                    float* __restrict__ pssm,
                                                    float* __restrict__ cons,
                                                    float* __restrict__ mi) {
    __shared__ int h_s[2 * 16 * HB];   // 14112 ints = 56448 B

    const int tid = threadIdx.x;
    const int w = tid >> 6;
    const int lane = tid & 63;
    const int bid = blockIdx.x;

    if (bid < NTILE) {
        // ======================== MI tile-pair part ========================
        int t = bid, ti = 0, off = 0;
        while (off + (NG - ti) <= t) { off += NG - ti; ++ti; }
        const int tj = ti + (t - off);
        const int i0 = ti * G, j0 = tj * G;
        const bool diag = (ti == tj);

        for (int k = tid; k < 2 * 16 * HB; k += 512) h_s[k] = 0;
        __syncthreads();

        const int half = tid >> 8;      // 0 or 1 (waves 0-3 vs 4-7)
        const int htid = tid & 255;
        int* H = h_s + half * (16 * HB);
#pragma unroll
        for (int k = 0; k < 4; ++k) {
            const int s = half * 1024 + htid + (k << 8);
            const int* rp = msa + (size_t)s * SEQ_LEN;
            const int4 va = *(const int4*)(rp + i0);
            const int4 vb = *(const int4*)(rp + j0);
            const int A0 = va.x * NS, A1 = va.y * NS, A2 = va.z * NS, A3 = va.w * NS;
#define UPD(PI, PJ, AA, BB) atomicAdd(&H[(PI * 4 + PJ) * HB + AA + BB], 1)
            UPD(0, 0, A0, vb.x); UPD(0, 1, A0, vb.y); UPD(0, 2, A0, vb.z); UPD(0, 3, A0, vb.w);
            UPD(1, 0, A1, vb.x); UPD(1, 1, A1, vb.y); UPD(1, 2, A1, vb.z); UPD(1, 3, A1, vb.w);
            UPD(2, 0, A2, vb.x); UPD(2, 1, A2, vb.y); UPD(2, 2, A2, vb.z); UPD(2, 3, A2, vb.w);
            UPD(3, 0, A3, vb.x); UPD(3, 1, A3, vb.y); UPD(3, 2, A3, vb.z); UPD(3, 3, A3, vb.w);
#undef UPD
        }
        __syncthreads();

        // finish: wave w handles pairs 2w and 2w+1 (16 pairs over 8 waves)
#pragma unroll
        for (int q = 0; q < 2; ++q) {
            const int p = w * 2 + q;
            const int pi = p >> 2, pj = p & 3;
            if (diag && pi >= pj) continue;       // wave-uniform skip
            const int* hA = h_s + p * HB;
            const int* hB = h_s + 16 * HB + p * HB;

            float mterm = 0.f, tpart = 0.f;
            if (lane < NAA) {
                int ssum = 0;
#pragma unroll
                for (int b = 0; b < NAA; ++b)
                    ssum += hA[lane * NS + b] + hB[lane * NS + b];
                if (ssum > 0) {
                    const float R = (float)ssum;
                    tpart = R;
                    mterm = R * __log2f(R);
                }
            } else if (lane >= 32 && lane < 32 + NAA) {
                const int c = lane - 32;
                int ssum = 0;
#pragma unroll
                for (int a = 0; a < NAA; ++a)
                    ssum += hA[a * NS + c] + hB[a * NS + c];
                if (ssum > 0) {
                    const float C = (float)ssum;
                    mterm = C * __log2f(C);
                }
            }

            float part = -mterm;   // Sum J lgJ - Sum Ra lgRa - Sum Cb lgCb
#pragma unroll
            for (int u = 0; u < 7; ++u) {
                const int k2 = lane + (u << 6);
                if (k2 < NAA * NAA) {
                    const int row = k2 / NAA;
                    const int col = k2 - row * NAA;
                    const int J = hA[row * NS + col] + hB[row * NS + col];
                    if (J > 0) {
                        const float fJ = (float)J;
                        part += fJ * __log2f(fJ);
                    }
                }
            }
#pragma unroll
            for (int o = 32; o; o >>= 1) {
                part += __shfl_down(part, o, 64);
                tpart += __shfl_down(tpart, o, 64);
            }
            if (lane == 0) {
                const float m = (tpart > 0.f)
                                    ? __fdividef(part, tpart) + __log2f(tpart)
                                    : 0.f;
                mi[(size_t)(i0 + pi) * SEQ_LEN + (j0 + pj)] = m;
                mi[(size_t)(j0 + pj) * SEQ_LEN + (i0 + pi)] = m;
            }
        }
    } else {
        // ========================== position part ==========================
        const int pb = bid - NTILE;      // 0..63
        const int i0 = pb * 8;

        // zero MI rows i0..i0+7 (race-free: MI blocks own off-diag [0,100)^2)
        for (int r = 0; r < 8; ++r) {
            const int i = i0 + r;
            float* rowp = mi + (size_t)i * SEQ_LEN;
            if (i < MPOS) {
                const int c = MPOS + tid;
                if (c < SEQ_LEN) rowp[c] = 0.f;
                if (tid == 0) rowp[i] = 0.f;
            } else {
                if (tid < SEQ_LEN / 4)
                    ((float4*)rowp)[tid] = make_float4(0.f, 0.f, 0.f, 0.f);
            }
        }

        // per-wave 8x21 histograms: h_s[w*168 + p*21 + a]
        for (int k = tid; k < 8 * 8 * NS; k += 512) h_s[k] = 0;
        __syncthreads();

        int* h = h_s + w * (8 * NS);
#pragma unroll
        for (int k = 0; k < 4; ++k) {
            const int s = tid + (k << 9);
            const int* rp = msa + (size_t)s * SEQ_LEN + i0;
            const int4 v0 = *(const int4*)rp;
            const int4 v1 = *(const int4*)(rp + 4);
            atomicAdd(&h[0 * NS + v0.x], 1);
            atomicAdd(&h[1 * NS + v0.y], 1);
            atomicAdd(&h[2 * NS + v0.z], 1);
            atomicAdd(&h[3 * NS + v0.w], 1);
            atomicAdd(&h[4 * NS + v1.x], 1);
            atomicAdd(&h[5 * NS + v1.y], 1);
            atomicAdd(&h[6 * NS + v1.z], 1);
            atomicAdd(&h[7 * NS + v1.w], 1);
        }
        __syncthreads();

        float* cntf = (float*)(h_s + 2048);   // beyond the 1344 used ints
        if (tid < 8 * NAA) {
            const int p = tid / NAA, a = tid - p * NAA;
            const int idx = p * NS + a;
            int c = 0;
#pragma unroll
            for (int ww = 0; ww < 8; ++ww) c += h_s[ww * (8 * NS) + idx];
            cntf[tid] = (float)c;
            const float pcnt = 0.01f * pc[0];
            const float freq = __fdividef((float)c + pcnt, 2048.0f + pcnt * 20.0f);
            pssm[(size_t)(i0 + p) * NAA + a] = __logf(freq * 20.0f + 1e-10f);
        }
        __syncthreads();

        // conservation: 8 groups of 32 threads (waves 0-3)
        if (tid < 256) {
            const int p = tid >> 5, l = tid & 31;
            const float fc = (l < NAA) ? cntf[p * NAA + l] : 0.f;
            float tt = fc;
#pragma unroll
            for (int o = 16; o; o >>= 1) tt += __shfl_xor(tt, o, 32);
            const float ts2 = fmaxf(tt, 1.f);
            const float f = __fdividef(fc, ts2);
            float term = (l < NAA) ? -f * __log2f(f + 1e-10f) : 0.f;
#pragma unroll
            for (int o = 16; o; o >>= 1) term += __shfl_xor(term, o, 32);
            if (l == 0)
                cons[i0 + p] = (tt > 0.f) ? (1.f - term * 0.2313782131597592f) : 0.f;
        }
    }
}

// ---------------------------------------------------------------------------
extern "C" void kernel_launch(void* const* d_in, const int* in_sizes, int n_in,
                              void* d_out, int out_size, void* d_ws, size_t ws_size,
                              hipStream_t stream) {
    const int* msa = (const int*)d_in[0];
    const float* pc = (const float*)d_in[1];

    float* pssm = (float*)d_out;         // 512*20
    float* cons = pssm + SEQ_LEN * NAA;  // 512
    float* mi = cons + SEQ_LEN;          // 512*512

    fused_kernel<<<NBLK, 512, 0, stream>>>(msa, pc, pssm, cons, mi);
}